// Round 4
// baseline (346.109 us; speedup 1.0000x reference)
//
#include <hip/hip_runtime.h>

// Problem constants (fixed by reference setup_inputs)
#define BT    16384          // b*t = 4*4096
#define TSEQ  4096           // time steps per batch
#define DM    1024           // d_model
#define EXP   1024           // expanded
#define N1    2048           // 2*EXP
#define KDIM  1024           // GEMM K (both GEMMs)
#define NKT   (KDIM / 64)    // 16 K-tiles
#define EPSV  1e-8f

typedef __bf16 bf16x8 __attribute__((ext_vector_type(8)));
typedef float f32x16 __attribute__((ext_vector_type(16)));
typedef unsigned short u16x8 __attribute__((ext_vector_type(8)));

#define AS1CAST(p) ((__attribute__((address_space(1))) void*)(p))
#define AS3CAST(p) ((__attribute__((address_space(3))) void*)(p))

__device__ __forceinline__ unsigned short f2bf(float f) {
    unsigned int u = __float_as_uint(f);
    u += 0x7fffu + ((u >> 16) & 1u);
    return (unsigned short)(u >> 16);
}

// ---------------------------------------------------------------------------
// fp32 -> bf16 conversion for all three inputs in ONE launch (4 elems/thread).
__global__ __launch_bounds__(256) void k_f2bf3(const float* __restrict__ i0, unsigned short* __restrict__ o0, int n0,
                                               const float* __restrict__ i1, unsigned short* __restrict__ o1, int n1,
                                               const float* __restrict__ i2, unsigned short* __restrict__ o2, int n2) {
    int i = blockIdx.x * 256 + threadIdx.x;
    const float* in; unsigned short* out;
    if (i < n0)                { in = i0; out = o0; }
    else if (i < n0 + n1)      { in = i1; out = o1; i -= n0; }
    else if (i < n0 + n1 + n2) { in = i2; out = o2; i -= n0 + n1; }
    else return;
    float4 v = ((const float4*)in)[i];
    ushort4 o;
    o.x = f2bf(v.x); o.y = f2bf(v.y); o.z = f2bf(v.z); o.w = f2bf(v.w);
    ((ushort4*)out)[i] = o;
}

// ---------------------------------------------------------------------------
// bf16 GEMM, C[m,n] = sum_k A[m,k]*B[n,k] + bias[n]
// 128x128 tile, 128 threads = 2 waves; waves PARTITION M (wave w owns rows
// w*64..w*64+63) so A fragments are wave-private -> loaded global->VGPR
// directly (each row's kt-window = one 128B line, L1-resident), double-
// buffered across kt. Only B is staged through LDS (16 KB, quarter-swizzled
// (q+row)&7 for the minimal 8-lane/granule bank pattern). Wave tile
// 64x128 = 2x4 grid of 32x32x16 MFMA (128 AGPR).
// Epilogue: per-row sumsq (half-wave shuffle + atomicAdd) for RMSNorm.
template <int BF16_OUT>
__device__ __forceinline__ void gemm_body(const unsigned short* __restrict__ A,
                                          const unsigned short* __restrict__ Bw,
                                          const float* __restrict__ bias,
                                          unsigned short* __restrict__ Cb,
                                          float* __restrict__ Cf,
                                          float* __restrict__ ssq,
                                          int N) {
    __shared__ unsigned short sB[128 * 64];   // 16 KB

    const int tid  = threadIdx.x;
    const int lane = tid & 63;
    const int w    = tid >> 6;
    const int ln   = lane & 31;
    const int hi   = lane >> 5;
    const int row0 = blockIdx.y * 128, col0 = blockIdx.x * 128;

    // A direct: wave-private rows w*64 + i*32 + ln; lane reads 16B at
    // k = kt*64 + ks*16 + hi*8.
    const unsigned short* aRow0 = A + (size_t)(row0 + w * 64 + ln) * KDIM + hi * 8;
    const unsigned short* aRow1 = aRow0 + (size_t)32 * KDIM;

    // B staging: slot s = b*128 + tid; row r = s>>3, phys quarter = tid&7,
    // logical quarter q = ((tid&7) - r) & 7 (kt-independent).
    const int r_b = tid >> 3;
    const int q_b = ((tid & 7) - r_b) & 7;
    const unsigned short* bSrc = Bw + (size_t)(col0 + r_b) * KDIM + q_b * 8;

    f32x16 acc[2][4] = {};

    auto loadA = [&](bf16x8* ar, int kt) {
#pragma unroll
        for (int ks = 0; ks < 4; ++ks) {
            ar[ks]     = *(const bf16x8*)(aRow0 + kt * 64 + ks * 16);
            ar[4 + ks] = *(const bf16x8*)(aRow1 + kt * 64 + ks * 16);
        }
    };
    auto stageB = [&](int kt) {
#pragma unroll
        for (int b = 0; b < 8; ++b)
            __builtin_amdgcn_global_load_lds(AS1CAST(bSrc + (size_t)b * 16 * KDIM + kt * 64),
                                             AS3CAST(&sB[(b * 128 + w * 64) * 8]), 16, 0, 0);
    };
    auto compute = [&](const bf16x8* ar) {
#pragma unroll
        for (int ks = 0; ks < 4; ++ks) {
            const int sw = ((ks * 2 + hi + ln) & 7) * 8;   // swizzled quarter
            bf16x8 bF[4];
#pragma unroll
            for (int j = 0; j < 4; ++j)
                bF[j] = *(const bf16x8*)&sB[(j * 32 + ln) * 64 + sw];
#pragma unroll
            for (int i = 0; i < 2; ++i)
#pragma unroll
                for (int j = 0; j < 4; ++j)
                    acc[i][j] = __builtin_amdgcn_mfma_f32_32x32x16_bf16(
                        ar[i * 4 + ks], bF[j], acc[i][j], 0, 0, 0);
        }
    };

    bf16x8 a0[8], a1[8];
    loadA(a0, 0);
    for (int kt = 0; kt < NKT; kt += 2) {
        __syncthreads();                 // sB consumers of kt-1 done
        stageB(kt);
        loadA(a1, kt + 1);               // overlaps barrier drain
        __syncthreads();
        compute(a0);
        __syncthreads();
        stageB(kt + 1);
        if (kt + 2 < NKT) loadA(a0, kt + 2);
        __syncthreads();
        compute(a1);
    }

    // epilogue — C/D: col = lane&31 (+j*32), row = (reg&3) + 8*(reg>>2) + 4*hi
    const int c0 = col0 + ln;
    float bs[4];
#pragma unroll
    for (int j = 0; j < 4; ++j) bs[j] = bias[c0 + j * 32];

#pragma unroll
    for (int i = 0; i < 2; ++i) {
        const int rb = row0 + w * 64 + i * 32 + 4 * hi;
#pragma unroll
        for (int reg = 0; reg < 16; ++reg) {
            const int gm = rb + (reg & 3) + 8 * (reg >> 2);
            float v[4]; float p = 0.f;
#pragma unroll
            for (int j = 0; j < 4; ++j) {
                v[j] = acc[i][j][reg] + bs[j];
                p += v[j] * v[j];
            }
#pragma unroll
            for (int off = 1; off < 32; off <<= 1) p += __shfl_xor(p, off, 64);
            if (ln == 0) atomicAdd(&ssq[gm], p);
            size_t base = (size_t)gm * N + c0;
#pragma unroll
            for (int j = 0; j < 4; ++j) {
                if (BF16_OUT) Cb[base + j * 32] = f2bf(v[j]);
                else          Cf[base + j * 32] = v[j];
            }
        }
    }
}

__global__ __launch_bounds__(128, 2) void k_gemm_in(const unsigned short* __restrict__ A,
                                                    const unsigned short* __restrict__ Bw,
                                                    const float* __restrict__ bias,
                                                    unsigned short* __restrict__ Cb,
                                                    float* __restrict__ ssq) {
    gemm_body<1>(A, Bw, bias, Cb, nullptr, ssq, N1);
}

__global__ __launch_bounds__(128, 2) void k_gemm_out(const unsigned short* __restrict__ A,
                                                     const unsigned short* __restrict__ Bw,
                                                     const float* __restrict__ bias,
                                                     float* __restrict__ Cf,
                                                     float* __restrict__ ssq) {
    gemm_body<0>(A, Bw, bias, nullptr, Cf, ssq, DM);
}

// ---------------------------------------------------------------------------
// RMSNorm(z) -> split x|v -> depthwise conv(K=3, same, per-batch) -> gate
// 2 tokens / block; 128 threads/token; 8 channels/thread.
__global__ __launch_bounds__(256) void k_conv_gate(const unsigned short* __restrict__ z,
                                                   const float* __restrict__ ssq1,
                                                   const float* __restrict__ inw,
                                                   const float* __restrict__ cw,
                                                   const float* __restrict__ cb,
                                                   unsigned short* __restrict__ g) {
    const int tok = blockIdx.x * 2 + (threadIdx.x >> 7);
    const int e8  = (threadIdx.x & 127) * 8;
    const int t   = tok & (TSEQ - 1);

    const float rs0 = rsqrtf(ssq1[tok] * (1.0f / N1) + EPSV);
    const int tm = (t > 0) ? tok - 1 : tok;
    const int tp = (t < TSEQ - 1) ? tok + 1 : tok;
    const float rsm = (t > 0) ? rsqrtf(ssq1[tm] * (1.0f / N1) + EPSV) : 0.0f;
    const float rsp = (t < TSEQ - 1) ? rsqrtf(ssq1[tp] * (1.0f / N1) + EPSV) : 0.0f;

    bf16x8 xm = *(const bf16x8*)(z + (size_t)tm * N1 + e8);
    bf16x8 x0 = *(const bf16x8*)(z + (size_t)tok * N1 + e8);
    bf16x8 xp = *(const bf16x8*)(z + (size_t)tp * N1 + e8);
    bf16x8 vv = *(const bf16x8*)(z + (size_t)tok * N1 + EXP + e8);

    u16x8 ov;
#pragma unroll
    for (int p = 0; p < 8; ++p) {
        const int e = e8 + p;
        const float we  = inw[e];
        const float wvv = inw[EXP + e];
        const float w0 = cw[e * 3], w1 = cw[e * 3 + 1], w2 = cw[e * 3 + 2];
        float y = w0 * ((float)xm[p] * rsm * we)
                + w1 * ((float)x0[p] * rs0 * we)
                + w2 * ((float)xp[p] * rsp * we)
                + cb[e];
        float vn = (float)vv[p] * rs0 * wvv;
        ov[p] = f2bf(vn * y);
    }
    *(u16x8*)(g + (size_t)tok * EXP + e8) = ov;
}

// ---------------------------------------------------------------------------
// Final RMSNorm scale in place on fp32 output: out *= rsqrt(mean)*w
__global__ __launch_bounds__(256) void k_outnorm(float* __restrict__ o,
                                                 const float* __restrict__ ssq2,
                                                 const float* __restrict__ onw) {
    const int idx = blockIdx.x * 256 + threadIdx.x;   // one float4
    const int tok = idx >> 8;                         // 256 float4 per token
    const int d4  = (idx & 255) * 4;
    const float rs = rsqrtf(ssq2[tok] * (1.0f / DM) + EPSV);
    float4 v = ((float4*)o)[idx];
    float4 w = *(const float4*)(onw + d4);
    v.x *= rs * w.x; v.y *= rs * w.y; v.z *= rs * w.z; v.w *= rs * w.w;
    ((float4*)o)[idx] = v;
}

// ---------------------------------------------------------------------------
extern "C" void kernel_launch(void* const* d_in, const int* in_sizes, int n_in,
                              void* d_out, int out_size, void* d_ws, size_t ws_size,
                              hipStream_t stream) {
    const float* u     = (const float*)d_in[0];
    const float* W_in  = (const float*)d_in[1];
    const float* b_in  = (const float*)d_in[2];
    const float* inw   = (const float*)d_in[3];
    const float* cw    = (const float*)d_in[4];
    const float* cb    = (const float*)d_in[5];
    const float* W_out = (const float*)d_in[6];
    const float* b_out = (const float*)d_in[7];
    const float* onw   = (const float*)d_in[8];
    float* out = (float*)d_out;

    char* ws = (char*)d_ws;
    unsigned short* u_bf    = (unsigned short*)ws; ws += (size_t)BT * DM * 2;     // 32 MB
    unsigned short* Win_bf  = (unsigned short*)ws; ws += (size_t)N1 * DM * 2;     //  4 MB
    unsigned short* Wout_bf = (unsigned short*)ws; ws += (size_t)DM * EXP * 2;    //  2 MB
    unsigned short* z_bf    = (unsigned short*)ws; ws += (size_t)BT * N1 * 2;     // 64 MB
    unsigned short* g_bf    = (unsigned short*)ws; ws += (size_t)BT * EXP * 2;    // 32 MB
    float* ssq1 = (float*)ws; ws += (size_t)BT * 4;
    float* ssq2 = (float*)ws; ws += (size_t)BT * 4;

    hipMemsetAsync(ssq1, 0, (size_t)BT * 2 * sizeof(float), stream);  // ssq1+ssq2 adjacent

    const int n0 = BT * DM / 4, n1c = N1 * DM / 4, n2c = DM * EXP / 4;
    k_f2bf3<<<(n0 + n1c + n2c + 255) / 256, 256, 0, stream>>>(u, u_bf, n0,
                                                              W_in, Win_bf, n1c,
                                                              W_out, Wout_bf, n2c);

    dim3 gA(N1 / 128, BT / 128);   // (16,128)
    k_gemm_in<<<gA, 128, 0, stream>>>(u_bf, Win_bf, b_in, z_bf, ssq1);

    k_conv_gate<<<BT / 2, 256, 0, stream>>>(z_bf, ssq1, inw, cw, cb, g_bf);

    dim3 gC(DM / 128, BT / 128);   // (8,128)
    k_gemm_out<<<gC, 128, 0, stream>>>(g_bf, Wout_bf, b_out, out, ssq2);

    k_outnorm<<<BT, 256, 0, stream>>>(out, ssq2, onw);

    (void)in_sizes; (void)n_in; (void)out_size; (void)ws_size;
}